// Round 4
// baseline (60.006 us; speedup 1.0000x reference)
//
#include <hip/hip_runtime.h>

// Zernike SH (l=0..3) + per-degree 4-unit dense, fused, write-BW-bound.
//
// Two-phase LDS design:
//  Phase 1: thread = point. n2 + 15 SH scalars once; pre-fold row0 (G0)
//           and l=1 factor (G1); 24-f32 record per point in LDS.
//  Phase 2: thread-task = one (point, m) float4. m = tid&15 is
//           LOOP-INVARIANT -> all weight/offset selection hoisted; body is
//           {ds_read s, ds_read G(broadcast), 4 sel+mul, nt store}.
//           Stores: consecutive float4 per lane -> 1 KB/wave, nontemporal
//           via native ext_vector_type (HIP float4 struct is rejected by
//           __builtin_nontemporal_store).

typedef float f32x4 __attribute__((ext_vector_type(4)));

#define C0f   0.28209479177387814f
#define C1f   0.4886025119029199f
#define C2XYf 1.0925484305920792f
#define C20f  0.31539156525252005f
#define C22f  0.5462742152960396f
#define C33f  0.5900435899266435f
#define C32f  2.890611442640554f
#define C31f  0.4570457994644658f
#define C30f  0.3731763325901154f
#define C3P2f 1.445305721320277f

#define PTS_PER_BLOCK 256
#define REC 24  // f32 per point: [0:4)=G0(final row0), [4:8)=G1, [8:24)=s0..s15

__global__ __launch_bounds__(256) void zernike_fused(
    const float* __restrict__ x,
    const float* __restrict__ W0, const float* __restrict__ b0,
    const float* __restrict__ W1, const float* __restrict__ W2,
    const float* __restrict__ W3,
    f32x4* __restrict__ out, int npoints)
{
    __shared__ float sm[PTS_PER_BLOCK * REC];

    const int tid   = threadIdx.x;
    const int pbase = blockIdx.x * PTS_PER_BLOCK;

    // Wave-uniform weight prep (scalar loads).
    float a0[4], a1[4], g10[4], g11[4], w2r[4], w3r[4];
#pragma unroll
    for (int u = 0; u < 4; ++u) {
        a0[u]  = C0f * W0[u] + b0[u];
        a1[u]  = C0f * W0[4 + u];
        g10[u] = W1[u];
        g11[u] = W1[4 + u];
        w2r[u] = W2[u];
        w3r[u] = W3[u];
    }

    // ---- Phase 1: one point per thread ----
    {
        const int p = pbase + tid;
        if (p < npoints) {
            const float px = x[3 * p + 0];
            const float py = x[3 * p + 1];
            const float pz = x[3 * p + 2];
            const float x2 = px * px, y2 = py * py, z2 = pz * pz;
            const float n2 = x2 + y2 + z2;

            float* rec = &sm[tid * REC];

            f32x4 G0, G1;
            G0.x = fmaf(n2, a1[0], a0[0]);   G0.y = fmaf(n2, a1[1], a0[1]);
            G0.z = fmaf(n2, a1[2], a0[2]);   G0.w = fmaf(n2, a1[3], a0[3]);
            G1.x = fmaf(n2, g11[0], g10[0]); G1.y = fmaf(n2, g11[1], g10[1]);
            G1.z = fmaf(n2, g11[2], g10[2]); G1.w = fmaf(n2, g11[3], g10[3]);
            *(f32x4*)(rec + 0) = G0;
            *(f32x4*)(rec + 4) = G1;

            rec[8]  = 1.0f;
            rec[9]  = C1f * py;
            rec[10] = C1f * pz;
            rec[11] = C1f * px;
            rec[12] = C2XYf * px * py;
            rec[13] = C2XYf * py * pz;
            rec[14] = C20f * (2.0f * z2 - x2 - y2);
            rec[15] = C2XYf * px * pz;
            rec[16] = C22f * (x2 - y2);
            rec[17] = C33f * py * (3.0f * x2 - y2);
            rec[18] = C32f * px * py * pz;
            rec[19] = C31f * py * (4.0f * z2 - x2 - y2);
            rec[20] = C30f * pz * (2.0f * z2 - 3.0f * x2 - 3.0f * y2);
            rec[21] = C31f * px * (4.0f * z2 - x2 - y2);
            rec[22] = C3P2f * pz * (x2 - y2);
            rec[23] = C33f * px * (x2 - 3.0f * y2);
        }
    }
    __syncthreads();

    // ---- Phase 2: 16 float4 stores/thread; all m-dependent state hoisted ----
    const int plb = tid >> 4;        // local point base 0..15 (k adds 16 each iter)
    const int m   = tid & 15;        // loop-invariant output row

    // Per-thread constants:
    const bool useG = (m < 4);
    const int  goff = (m == 0) ? 0 : 4;          // G0 vs G1 (f32 idx)
    f32x4 wreg;
    {
        const int sel = (m < 9) ? 0 : 1;
        wreg.x = sel ? w3r[0] : w2r[0];
        wreg.y = sel ? w3r[1] : w2r[1];
        wreg.z = sel ? w3r[2] : w2r[2];
        wreg.w = sel ? w3r[3] : w2r[3];
    }
    const int soff = 8 + m;

    f32x4* op = out + (size_t)blockIdx.x * (PTS_PER_BLOCK * 16) + tid;

#pragma unroll 8
    for (int k = 0; k < 16; ++k) {
        const float* rec = &sm[(k * 16 + plb) * REC];
        const float  s   = rec[soff];
        const f32x4  g   = *(const f32x4*)(rec + goff);   // broadcast-heavy

        f32x4 r;
        r.x = s * (useG ? g.x : wreg.x);
        r.y = s * (useG ? g.y : wreg.y);
        r.z = s * (useG ? g.z : wreg.z);
        r.w = s * (useG ? g.w : wreg.w);

        __builtin_nontemporal_store(r, op);
        op += 256;
    }
}

extern "C" void kernel_launch(void* const* d_in, const int* in_sizes, int n_in,
                              void* d_out, int out_size, void* d_ws, size_t ws_size,
                              hipStream_t stream) {
    const float* x  = (const float*)d_in[0];
    const float* W0 = (const float*)d_in[1];
    const float* b0 = (const float*)d_in[2];
    const float* W1 = (const float*)d_in[3];
    const float* W2 = (const float*)d_in[4];
    const float* W3 = (const float*)d_in[5];

    const int npoints = in_sizes[0] / 3;                                // 1,048,576
    const int blocks  = (npoints + PTS_PER_BLOCK - 1) / PTS_PER_BLOCK;  // 4096

    zernike_fused<<<blocks, 256, 0, stream>>>(
        x, W0, b0, W1, W2, W3, (f32x4*)d_out, npoints);
}

// Round 5
// 49.220 us; speedup vs baseline: 1.2191x; 1.2191x over previous
//
#include <hip/hip_runtime.h>

// Zernike SH (l=0..3) + per-degree 4-unit dense, fused, write-BW-bound.
//
// Two-phase LDS design:
//  Phase 1: thread = point. n2 + 15 SH scalars once; pre-fold row0 (G0)
//           and l=1 factor (G1); 24-f32 record per point in LDS.
//  Phase 2: thread-task = one (point, m) float4. m = tid&15 loop-invariant;
//           all selection hoisted; 16 iters FULLY unrolled so ds_reads fold
//           into offset: immediates and 16 stores pipeline.
//  NOTE (R4 lesson): __builtin_nontemporal_store on this stream = -20% BW
//  (bypasses L2 write aggregation). Use plain stores.

typedef float f32x4 __attribute__((ext_vector_type(4)));

#define C0f   0.28209479177387814f
#define C1f   0.4886025119029199f
#define C2XYf 1.0925484305920792f
#define C20f  0.31539156525252005f
#define C22f  0.5462742152960396f
#define C33f  0.5900435899266435f
#define C32f  2.890611442640554f
#define C31f  0.4570457994644658f
#define C30f  0.3731763325901154f
#define C3P2f 1.445305721320277f

#define PTS_PER_BLOCK 256
#define REC 24  // f32 per point: [0:4)=G0(final row0), [4:8)=G1, [8:24)=s0..s15

__global__ __launch_bounds__(256) void zernike_fused(
    const float* __restrict__ x,
    const float* __restrict__ W0, const float* __restrict__ b0,
    const float* __restrict__ W1, const float* __restrict__ W2,
    const float* __restrict__ W3,
    f32x4* __restrict__ out, int npoints)
{
    __shared__ float sm[PTS_PER_BLOCK * REC];

    const int tid   = threadIdx.x;
    const int pbase = blockIdx.x * PTS_PER_BLOCK;

    // Wave-uniform weight prep (scalar loads).
    float a0[4], a1[4], g10[4], g11[4], w2r[4], w3r[4];
#pragma unroll
    for (int u = 0; u < 4; ++u) {
        a0[u]  = C0f * W0[u] + b0[u];
        a1[u]  = C0f * W0[4 + u];
        g10[u] = W1[u];
        g11[u] = W1[4 + u];
        w2r[u] = W2[u];
        w3r[u] = W3[u];
    }

    // ---- Phase 1: one point per thread ----
    {
        const int p = pbase + tid;
        if (p < npoints) {
            const float px = x[3 * p + 0];
            const float py = x[3 * p + 1];
            const float pz = x[3 * p + 2];
            const float x2 = px * px, y2 = py * py, z2 = pz * pz;
            const float n2 = x2 + y2 + z2;

            float* rec = &sm[tid * REC];

            f32x4 G0, G1;
            G0.x = fmaf(n2, a1[0], a0[0]);   G0.y = fmaf(n2, a1[1], a0[1]);
            G0.z = fmaf(n2, a1[2], a0[2]);   G0.w = fmaf(n2, a1[3], a0[3]);
            G1.x = fmaf(n2, g11[0], g10[0]); G1.y = fmaf(n2, g11[1], g10[1]);
            G1.z = fmaf(n2, g11[2], g10[2]); G1.w = fmaf(n2, g11[3], g10[3]);
            *(f32x4*)(rec + 0) = G0;
            *(f32x4*)(rec + 4) = G1;

            rec[8]  = 1.0f;
            rec[9]  = C1f * py;
            rec[10] = C1f * pz;
            rec[11] = C1f * px;
            rec[12] = C2XYf * px * py;
            rec[13] = C2XYf * py * pz;
            rec[14] = C20f * (2.0f * z2 - x2 - y2);
            rec[15] = C2XYf * px * pz;
            rec[16] = C22f * (x2 - y2);
            rec[17] = C33f * py * (3.0f * x2 - y2);
            rec[18] = C32f * px * py * pz;
            rec[19] = C31f * py * (4.0f * z2 - x2 - y2);
            rec[20] = C30f * pz * (2.0f * z2 - 3.0f * x2 - 3.0f * y2);
            rec[21] = C31f * px * (4.0f * z2 - x2 - y2);
            rec[22] = C3P2f * pz * (x2 - y2);
            rec[23] = C33f * px * (x2 - 3.0f * y2);
        }
    }
    __syncthreads();

    // ---- Phase 2: 16 float4 stores/thread; all m-dependent state hoisted ----
    const int plb = tid >> 4;        // local point base (k adds 16 each iter)
    const int m   = tid & 15;        // loop-invariant output row

    const bool useG = (m < 4);
    const int  goff = (m == 0) ? 0 : 4;          // G0 vs G1 (f32 idx)
    f32x4 wreg;
    {
        const int sel = (m < 9) ? 0 : 1;
        wreg.x = sel ? w3r[0] : w2r[0];
        wreg.y = sel ? w3r[1] : w2r[1];
        wreg.z = sel ? w3r[2] : w2r[2];
        wreg.w = sel ? w3r[3] : w2r[3];
    }

    // One LDS base; per-k addresses become offset: immediates (k*REC*16*4B).
    const float* rec0 = &sm[plb * REC];
    f32x4* op = out + (size_t)blockIdx.x * (PTS_PER_BLOCK * 16) + tid;

#pragma unroll
    for (int k = 0; k < 16; ++k) {
        const float* rec = rec0 + k * (16 * REC);
        const float  s   = rec[8 + m];
        const f32x4  g   = *(const f32x4*)(rec + goff);   // broadcast-heavy

        f32x4 r;
        r.x = s * (useG ? g.x : wreg.x);
        r.y = s * (useG ? g.y : wreg.y);
        r.z = s * (useG ? g.z : wreg.z);
        r.w = s * (useG ? g.w : wreg.w);

        op[k * 256] = r;
    }
}

extern "C" void kernel_launch(void* const* d_in, const int* in_sizes, int n_in,
                              void* d_out, int out_size, void* d_ws, size_t ws_size,
                              hipStream_t stream) {
    const float* x  = (const float*)d_in[0];
    const float* W0 = (const float*)d_in[1];
    const float* b0 = (const float*)d_in[2];
    const float* W1 = (const float*)d_in[3];
    const float* W2 = (const float*)d_in[4];
    const float* W3 = (const float*)d_in[5];

    const int npoints = in_sizes[0] / 3;                                // 1,048,576
    const int blocks  = (npoints + PTS_PER_BLOCK - 1) / PTS_PER_BLOCK;  // 4096

    zernike_fused<<<blocks, 256, 0, stream>>>(
        x, W0, b0, W1, W2, W3, (f32x4*)d_out, npoints);
}

// Round 6
// 49.198 us; speedup vs baseline: 1.2197x; 1.0004x over previous
//
#include <hip/hip_runtime.h>

// Zernike SH (l=0..3) + per-degree 4-unit dense, fused. Write-BW-bound.
//
// R5 redesign: BARRIER-FREE wave-autonomous streaming (fill-kernel regime).
//  - Each 256-thread block runs TILES=4 tiles of 256 points; wave w owns
//    points [64w,64w+64) of each tile and a private 6KB LDS slice.
//  - No __syncthreads anywhere -> compiler never force-drains vmcnt;
//    stores stay deep in flight across tile boundaries.
//  - Cross-lane LDS RAW within ONE wave: LDS pipe is in-order per wave;
//    enforce with explicit s_waitcnt lgkmcnt(0) + sched_barrier(0)
//    (compiler fence). No inter-wave LDS sharing at all.
//  - Next-tile x prefetch issued BEFORE the 16-store burst, so its vmcnt
//    wait resolves without draining the store queue.
//  - Plain stores (R4 lesson: nontemporal = -20% BW on this stream).

typedef float f32x4 __attribute__((ext_vector_type(4)));

#define C0f   0.28209479177387814f
#define C1f   0.4886025119029199f
#define C2XYf 1.0925484305920792f
#define C20f  0.31539156525252005f
#define C22f  0.5462742152960396f
#define C33f  0.5900435899266435f
#define C32f  2.890611442640554f
#define C31f  0.4570457994644658f
#define C30f  0.3731763325901154f
#define C3P2f 1.445305721320277f

#define PTS   256   // points per block-tile
#define REC   24    // f32/record: [0:4)=G0(final row0), [4:8)=G1, [8:24)=s0..s15
#define TILES 4     // tiles per block

__global__ __launch_bounds__(256) void zernike_fused(
    const float* __restrict__ x,
    const float* __restrict__ W0, const float* __restrict__ b0,
    const float* __restrict__ W1, const float* __restrict__ W2,
    const float* __restrict__ W3,
    f32x4* __restrict__ out, int npoints)
{
    __shared__ float sm[PTS * REC];

    const int tid  = threadIdx.x;
    const int wave = tid >> 6;
    const int lane = tid & 63;

    // Wave-uniform weight prep (scalar loads).
    float a0[4], a1[4], g10[4], g11[4], w2r[4], w3r[4];
#pragma unroll
    for (int u = 0; u < 4; ++u) {
        a0[u]  = C0f * W0[u] + b0[u];
        a1[u]  = C0f * W0[4 + u];
        g10[u] = W1[u];
        g11[u] = W1[4 + u];
        w2r[u] = W2[u];
        w3r[u] = W3[u];
    }

    // Wave-private LDS slice: 64 records.
    float* wbuf = &sm[(wave * 64) * REC];

    // Loop-invariant phase-2 selection state.
    const int  m    = lane & 15;
    const int  qrow = lane >> 4;           // 0..3
    const bool useG = (m < 4);
    const int  goff = (m == 0) ? 0 : 4;
    f32x4 wreg;
    {
        const int sel = (m < 9) ? 0 : 1;
        wreg.x = sel ? w3r[0] : w2r[0];
        wreg.y = sel ? w3r[1] : w2r[1];
        wreg.z = sel ? w3r[2] : w2r[2];
        wreg.w = sel ? w3r[3] : w2r[3];
    }

    const int tile0 = blockIdx.x * TILES;

    // Prefetch tile 0's point.
    float px, py, pz;
    {
        const int p  = tile0 * PTS + wave * 64 + lane;
        const int pc = p < npoints ? p : 0;
        px = x[3 * pc + 0]; py = x[3 * pc + 1]; pz = x[3 * pc + 2];
    }

    for (int t = 0; t < TILES; ++t) {
        const int tbase = (tile0 + t) * PTS;
        if (tbase >= npoints) break;                 // block-uniform

        // Fence: prior tile's ds_reads ordered before this tile's ds_writes
        // (wave-local; LDS pipe is in-order per wave — just stop the
        // compiler from reordering).
        __builtin_amdgcn_sched_barrier(0);

        // ---- Phase 1: this lane's record ----
        {
            const float x2 = px * px, y2 = py * py, z2 = pz * pz;
            const float n2 = x2 + y2 + z2;
            float* rec = &wbuf[lane * REC];

            f32x4 G0, G1, S0, S1, S2, S3;
            G0.x = fmaf(n2, a1[0], a0[0]);   G0.y = fmaf(n2, a1[1], a0[1]);
            G0.z = fmaf(n2, a1[2], a0[2]);   G0.w = fmaf(n2, a1[3], a0[3]);
            G1.x = fmaf(n2, g11[0], g10[0]); G1.y = fmaf(n2, g11[1], g10[1]);
            G1.z = fmaf(n2, g11[2], g10[2]); G1.w = fmaf(n2, g11[3], g10[3]);
            S0 = f32x4{1.0f, C1f * py, C1f * pz, C1f * px};
            S1 = f32x4{C2XYf * px * py,
                       C2XYf * py * pz,
                       C20f * (2.0f * z2 - x2 - y2),
                       C2XYf * px * pz};
            S2 = f32x4{C22f * (x2 - y2),
                       C33f * py * (3.0f * x2 - y2),
                       C32f * px * py * pz,
                       C31f * py * (4.0f * z2 - x2 - y2)};
            S3 = f32x4{C30f * pz * (2.0f * z2 - 3.0f * x2 - 3.0f * y2),
                       C31f * px * (4.0f * z2 - x2 - y2),
                       C3P2f * pz * (x2 - y2),
                       C33f * px * (x2 - 3.0f * y2)};
            *(f32x4*)(rec + 0)  = G0;
            *(f32x4*)(rec + 4)  = G1;
            *(f32x4*)(rec + 8)  = S0;
            *(f32x4*)(rec + 12) = S1;
            *(f32x4*)(rec + 16) = S2;
            *(f32x4*)(rec + 20) = S3;
        }

        // ---- Prefetch next tile's point (ahead of stores in vmcnt order) ----
        if (t + 1 < TILES) {
            const int p  = (tile0 + t + 1) * PTS + wave * 64 + lane;
            const int pc = p < npoints ? p : 0;
            px = x[3 * pc + 0]; py = x[3 * pc + 1]; pz = x[3 * pc + 2];
        }

        // Wave-sync: LDS writes complete before cross-lane reads.
        asm volatile("s_waitcnt lgkmcnt(0)" ::: "memory");
        __builtin_amdgcn_sched_barrier(0);

        // ---- Phase 2: 16 coalesced 1KB store iters, wave-local reads ----
        f32x4* op = out + (size_t)(tbase + wave * 64) * 16 + lane;

        if (tbase + PTS <= npoints) {
#pragma unroll
            for (int k = 0; k < 16; ++k) {
                const float* rec = &wbuf[(k * 4 + qrow) * REC];
                const float  s   = rec[8 + m];
                const f32x4  g   = *(const f32x4*)(rec + goff);
                f32x4 r;
                r.x = s * (useG ? g.x : wreg.x);
                r.y = s * (useG ? g.y : wreg.y);
                r.z = s * (useG ? g.z : wreg.z);
                r.w = s * (useG ? g.w : wreg.w);
                op[k * 64] = r;
            }
        } else {
            // Ragged tail (not hit for the benchmark shape).
            const int lim = (npoints - tbase - wave * 64) * 16;
#pragma unroll
            for (int k = 0; k < 16; ++k) {
                if (k * 64 + lane < lim) {
                    const float* rec = &wbuf[(k * 4 + qrow) * REC];
                    const float  s   = rec[8 + m];
                    const f32x4  g   = *(const f32x4*)(rec + goff);
                    f32x4 r;
                    r.x = s * (useG ? g.x : wreg.x);
                    r.y = s * (useG ? g.y : wreg.y);
                    r.z = s * (useG ? g.z : wreg.z);
                    r.w = s * (useG ? g.w : wreg.w);
                    op[k * 64] = r;
                }
            }
        }
    }
}

extern "C" void kernel_launch(void* const* d_in, const int* in_sizes, int n_in,
                              void* d_out, int out_size, void* d_ws, size_t ws_size,
                              hipStream_t stream) {
    const float* x  = (const float*)d_in[0];
    const float* W0 = (const float*)d_in[1];
    const float* b0 = (const float*)d_in[2];
    const float* W1 = (const float*)d_in[3];
    const float* W2 = (const float*)d_in[4];
    const float* W3 = (const float*)d_in[5];

    const int npoints = in_sizes[0] / 3;                       // 1,048,576
    const int per_blk = PTS * TILES;                           // 1024 points
    const int blocks  = (npoints + per_blk - 1) / per_blk;     // 1024

    zernike_fused<<<blocks, 256, 0, stream>>>(
        x, W0, b0, W1, W2, W3, (f32x4*)d_out, npoints);
}